// Round 3
// baseline (346.264 us; speedup 1.0000x reference)
//
#include <hip/hip_runtime.h>
#include <hip/hip_bf16.h>

#define IN_F  4096
#define OUT_F 11008
#define SEQ   512
#define NOUT  4096

#define BM 128
#define BN 64
#define BK 64
#define NT   (IN_F / BK)        // 64 K-phases
#define NBLK (OUT_F / BN)       // 172
#define MBLK (SEQ / BM)         // 4
#define NWG  (NBLK * MBLK)      // 688 = 8 * 86 -> bijective XCD swizzle

// ws layout: [0,4MB) X as bf16; then dedup'd outlier table
#define WS_TAB_I ((size_t)SEQ * IN_F * 2)
#define WS_TAB_F (WS_TAB_I + (size_t)NOUT * 4)

typedef __attribute__((ext_vector_type(8))) short bf16x8;
typedef __attribute__((ext_vector_type(4))) float f32x4;
typedef __attribute__((ext_vector_type(4))) int   int4v;
typedef __attribute__((ext_vector_type(4))) float float4v;

union Pack8 { bf16x8 v; __hip_bfloat16 h[8]; };

// ---- prep 1: X fp32 -> bf16 (vectorized, 8 elems/thread) ----
__global__ __launch_bounds__(256) void prep_x(const float* __restrict__ X,
                                              __hip_bfloat16* __restrict__ Xb) {
    const int i = (blockIdx.x * 256 + threadIdx.x) * 8;
    float4v x0 = *(const float4v*)(X + i);
    float4v x1 = *(const float4v*)(X + i + 4);
    Pack8 p;
    #pragma unroll
    for (int j = 0; j < 4; ++j) {
        p.h[j]     = __float2bfloat16(x0[j]);
        p.h[4 + j] = __float2bfloat16(x1[j]);
    }
    *(bf16x8*)(Xb + i) = p.v;
}

// ---- prep 2: dedup outliers (last-wins) + delta table ----
__global__ __launch_bounds__(256) void prep_tab(
    const int* __restrict__ oidx, const float* __restrict__ outv,
    const int* __restrict__ Q, const float* __restrict__ scale,
    int* __restrict__ tabi, float* __restrict__ tabf) {
    __shared__ unsigned long long sm[NOUT];   // 32 KB: (row,col) as u64
    for (int j = threadIdx.x; j < NOUT; j += 256)
        sm[j] = ((const unsigned long long*)oidx)[j];
    __syncthreads();
    const int j = blockIdx.x * 256 + threadIdx.x;
    const unsigned long long me = sm[j];
    bool dup = false;
    for (int j2 = j + 1; j2 < NOUT; ++j2) dup |= (sm[j2] == me);
    if (dup) { tabi[j] = -1; tabf[j] = 0.f; return; }
    const int r = oidx[2 * j], c = oidx[2 * j + 1];
    const float deq = __bfloat162float(__float2bfloat16(
        (float)Q[(size_t)r * IN_F + c] * scale[r]));
    tabi[j] = (r << 16) | c;
    tabf[j] = outv[j] - deq;
}

// ---- main: fused GEMM, 2-phase dbuf, counted vmcnt, raw barriers ----
__global__ __launch_bounds__(256) void qgemm3(
    const __hip_bfloat16* __restrict__ Xb,
    const int*   __restrict__ Q,
    const float* __restrict__ scale,
    const float* __restrict__ bias,
    const int*   __restrict__ tabi,
    const float* __restrict__ tabf,
    float* __restrict__ out)
{
    __shared__ __hip_bfloat16 sA[2][BM * BK];   // 32 KB, chunk-swizzled
    __shared__ __hip_bfloat16 sB[2][BN * BK];   // 16 KB, chunk-swizzled
    __shared__ int   list[256];
    __shared__ float ldel[256];
    __shared__ int   lcount;

    const int tid  = threadIdx.x;
    const int wave = tid >> 6;
    const int lane = tid & 63;

    // XCD-aware swizzle; 4 consecutive tiles share one Q panel (L2 reuse).
    const int lin = blockIdx.x;
    const int t0  = (lin & 7) * (NWG / 8) + (lin >> 3);
    const int col0 = (t0 >> 2) * BN;
    const int row0 = (t0 & 3) * BM;

    const int wm = (wave >> 1) * 64;
    const int wn = (wave & 1) * 32;
    const int fr = lane & 15;         // fragment row within 16
    const int fc = lane >> 4;         // k-chunk group 0..3

    f32x4 acc[4][2] = {};

    // A staging via global_load_lds: wave issues 4 loads, load i covers tile
    // rows (wave*4+i)*8..+7, LDS linear dest; SOURCE chunk XOR-swizzled so the
    // LDS layout has chunk s of row r holding logical chunk s^(r&7).
    const int arow = wave * 32 + (lane >> 3);
    const __hip_bfloat16* asrc =
        Xb + (size_t)(row0 + arow) * IN_F + (((lane & 7) ^ (lane >> 3)) * 8);
    auto issueA = [&](int buf, int k0) {
        #pragma unroll
        for (int i = 0; i < 4; ++i)
            __builtin_amdgcn_global_load_lds(
                (const __attribute__((address_space(1))) void*)(asrc + (size_t)i * 8 * IN_F + k0),
                (__attribute__((address_space(3))) void*)&sA[buf][(wave * 4 + i) * 8 * BK],
                16, 0, 0);
    };

    // B staging: thread covers Q row srb, 16 ints at k-offset skb; convert to
    // bf16 and ds_write with the same XOR chunk swizzle.
    const int srb = tid >> 2;
    const int skb = (tid & 3) * 16;
    const int* bsrc = Q + (size_t)(col0 + srb) * IN_F + skb;
    const float bscale = scale[col0 + srb];
    int4v b0, b1, b2, b3;
    auto writeB = [&](int buf) {
        Pack8 v0, v1;
        #pragma unroll
        for (int i = 0; i < 4; ++i) {
            v0.h[i]     = __float2bfloat16((float)b0[i] * bscale);
            v0.h[4 + i] = __float2bfloat16((float)b1[i] * bscale);
            v1.h[i]     = __float2bfloat16((float)b2[i] * bscale);
            v1.h[4 + i] = __float2bfloat16((float)b3[i] * bscale);
        }
        const int c0 = (tid & 3) * 2;
        const int s7 = srb & 7;
        *(bf16x8*)&sB[buf][srb * BK + ((c0 ^ s7) * 8)]       = v0.v;
        *(bf16x8*)&sB[buf][srb * BK + (((c0 + 1) ^ s7) * 8)] = v1.v;
    };

    // Prologue: tile0 into buf0, tile1 B-regs in flight across the barrier.
    issueA(0, 0);
    b0 = *(const int4v*)(bsrc + 0);
    b1 = *(const int4v*)(bsrc + 4);
    b2 = *(const int4v*)(bsrc + 8);
    b3 = *(const int4v*)(bsrc + 12);
    writeB(0);
    b0 = *(const int4v*)(bsrc + BK + 0);
    b1 = *(const int4v*)(bsrc + BK + 4);
    b2 = *(const int4v*)(bsrc + BK + 8);
    b3 = *(const int4v*)(bsrc + BK + 12);
    asm volatile("s_waitcnt vmcnt(4) lgkmcnt(0)" ::: "memory");
    __builtin_amdgcn_s_barrier();

    for (int t = 0; t < NT; ++t) {
        const int cur = t & 1;
        if (t + 1 < NT) issueA(cur ^ 1, (t + 1) * BK);

        // Fragment reads (swizzled slots; bank-balanced).
        bf16x8 fa[2][4], fb[2][2];
        #pragma unroll
        for (int kk = 0; kk < 2; ++kk) {
            #pragma unroll
            for (int mi = 0; mi < 4; ++mi) {
                const int row = wm + mi * 16 + fr;
                fa[kk][mi] = *(const bf16x8*)&sA[cur][row * BK + (((kk * 4 + fc) ^ (row & 7)) * 8)];
            }
            #pragma unroll
            for (int ni = 0; ni < 2; ++ni) {
                const int row = wn + ni * 16 + fr;
                fb[kk][ni] = *(const bf16x8*)&sB[cur][row * BK + (((kk * 4 + fc) ^ (row & 7)) * 8)];
            }
        }
        // Convert+write next B tile (waits only its own reg loads), then issue t+2.
        if (t + 1 < NT) writeB(cur ^ 1);
        if (t + 2 < NT) {
            b0 = *(const int4v*)(bsrc + (t + 2) * BK + 0);
            b1 = *(const int4v*)(bsrc + (t + 2) * BK + 4);
            b2 = *(const int4v*)(bsrc + (t + 2) * BK + 8);
            b3 = *(const int4v*)(bsrc + (t + 2) * BK + 12);
        }
        #pragma unroll
        for (int kk = 0; kk < 2; ++kk)
            #pragma unroll
            for (int mi = 0; mi < 4; ++mi)
                #pragma unroll
                for (int ni = 0; ni < 2; ++ni)
                    acc[mi][ni] = __builtin_amdgcn_mfma_f32_16x16x32_bf16(
                        fa[kk][mi], fb[kk][ni], acc[mi][ni], 0, 0, 0);

        // Publish: A gload_lds + B ds_write done; keep t+2 B-regs in flight.
        if (t + 2 < NT)
            asm volatile("s_waitcnt vmcnt(4) lgkmcnt(0)" ::: "memory");
        else
            asm volatile("s_waitcnt vmcnt(0) lgkmcnt(0)" ::: "memory");
        __builtin_amdgcn_s_barrier();
    }

    // Outlier deltas -> registers (no RMW, no atomics on global).
    if (tid == 0) lcount = 0;
    __syncthreads();
    for (int c = tid; c < NOUT; c += 256) {
        const int p = tabi[c];
        const int r = p >> 16;
        if (r >= col0 && r < col0 + BN) {
            const int pos = atomicAdd(&lcount, 1);
            if (pos < 256) { list[pos] = p; ldel[pos] = tabf[c]; }
        }
    }
    __syncthreads();
    const int nm = lcount < 256 ? lcount : 256;
    for (int u = 0; u < nm; ++u) {
        const int p    = list[u];
        const int ocl  = (p >> 16) - col0;   // 0..63
        const int ocol = p & 0xFFFF;
        if (((ocl >> 5) == (wave & 1)) && ((lane & 15) == (ocl & 15))) {
            const int ni = (ocl >> 4) & 1;
            const float d = ldel[u];
            #pragma unroll
            for (int mi = 0; mi < 4; ++mi)
                #pragma unroll
                for (int r2 = 0; r2 < 4; ++r2) {
                    const int grow = row0 + wm + mi * 16 + fc * 4 + r2;
                    acc[mi][ni][r2] += d * __bfloat162float(Xb[(size_t)grow * IN_F + ocol]);
                }
        }
    }

    // Epilogue: bias + store. C/D: col=lane&15, row=(lane>>4)*4+reg.
    const int er = fc * 4;
    const int ec = fr;
    #pragma unroll
    for (int ni = 0; ni < 2; ++ni) {
        const int gcol = col0 + wn + ni * 16 + ec;
        const float bv = bias[gcol];
        #pragma unroll
        for (int mi = 0; mi < 4; ++mi) {
            const int grow = row0 + wm + mi * 16 + er;
            #pragma unroll
            for (int r = 0; r < 4; ++r)
                out[(size_t)(grow + r) * OUT_F + gcol] = acc[mi][ni][r] + bv;
        }
    }
}

extern "C" void kernel_launch(void* const* d_in, const int* in_sizes, int n_in,
                              void* d_out, int out_size, void* d_ws, size_t ws_size,
                              hipStream_t stream) {
    const float* x    = (const float*)d_in[0];
    const int*   q    = (const int*)d_in[1];
    const float* qs   = (const float*)d_in[2];
    const float* qo   = (const float*)d_in[3];
    const int*   qi   = (const int*)d_in[4];
    const float* bias = (const float*)d_in[5];
    float* out = (float*)d_out;

    __hip_bfloat16* Xb = (__hip_bfloat16*)d_ws;
    int*   tabi = (int*)((char*)d_ws + WS_TAB_I);
    float* tabf = (float*)((char*)d_ws + WS_TAB_F);

    prep_x<<<dim3(SEQ * IN_F / 2048), 256, 0, stream>>>(x, Xb);
    prep_tab<<<dim3(NOUT / 256), 256, 0, stream>>>(qi, qo, q, qs, tabi, tabf);
    qgemm3<<<dim3(NWG), 256, 0, stream>>>(Xb, q, qs, bias, tabi, tabf, out);
}

// Round 4
// 143.838 us; speedup vs baseline: 2.4073x; 2.4073x over previous
//
#include <hip/hip_runtime.h>
#include <hip/hip_bf16.h>

#define IN_F  4096
#define OUT_F 11008
#define SEQ   512
#define NOUT  4096

#define BM 128
#define BN 64
#define BK 64
#define NT   (IN_F / BK)        // 64 K-phases
#define NBLK (OUT_F / BN)       // 172
#define MBLK (SEQ / BM)         // 4
#define NWG  (NBLK * MBLK)      // 688 = 8 * 86 -> bijective XCD swizzle

#define HSLOTS 8192             // dedup hash table (load factor 0.5)

// ws layout: [0,4MB) X as bf16; dedup'd outlier table; hash table
#define WS_TAB_I ((size_t)SEQ * IN_F * 2)
#define WS_TAB_F (WS_TAB_I + (size_t)NOUT * 4)
#define WS_HKEY  (WS_TAB_F + (size_t)NOUT * 4)
#define WS_HVAL  (WS_HKEY + (size_t)HSLOTS * 4)

typedef __attribute__((ext_vector_type(8))) short bf16x8;
typedef __attribute__((ext_vector_type(4))) float f32x4;
typedef __attribute__((ext_vector_type(4))) int   int4v;
typedef __attribute__((ext_vector_type(4))) float float4v;

union Pack8 { bf16x8 v; __hip_bfloat16 h[8]; };

__device__ __forceinline__ unsigned hslot(int key) {
    return ((unsigned)key * 2654435761u) & (HSLOTS - 1);
}

// ---- prep 1: X fp32 -> bf16 (vectorized) ----
__global__ __launch_bounds__(256) void prep_x(const float* __restrict__ X,
                                              __hip_bfloat16* __restrict__ Xb) {
    const int i = (blockIdx.x * 256 + threadIdx.x) * 8;
    float4v x0 = *(const float4v*)(X + i);
    float4v x1 = *(const float4v*)(X + i + 4);
    Pack8 p;
    #pragma unroll
    for (int j = 0; j < 4; ++j) {
        p.h[j]     = __float2bfloat16(x0[j]);
        p.h[4 + j] = __float2bfloat16(x1[j]);
    }
    *(bf16x8*)(Xb + i) = p.v;
}

// ---- prep 2a: init hash table ----
__global__ __launch_bounds__(256) void prep_hinit(int* __restrict__ hkey,
                                                  int* __restrict__ hval) {
    const int i = blockIdx.x * 256 + threadIdx.x;
    hkey[i] = -1;
    hval[i] = -1;
}

// ---- prep 2b: insert outliers, last-wins via atomicMax on entry index ----
__global__ __launch_bounds__(256) void prep_hins(const int* __restrict__ oidx,
                                                 int* __restrict__ hkey,
                                                 int* __restrict__ hval) {
    const int j = blockIdx.x * 256 + threadIdx.x;
    const int key = oidx[2 * j] * IN_F + oidx[2 * j + 1];
    unsigned s = hslot(key);
    while (true) {
        const int prev = atomicCAS(&hkey[s], -1, key);
        if (prev == -1 || prev == key) break;
        s = (s + 1) & (HSLOTS - 1);
    }
    atomicMax(&hval[s], j);
}

// ---- prep 2c: resolve dups + delta table ----
__global__ __launch_bounds__(256) void prep_tab(
    const int* __restrict__ oidx, const float* __restrict__ outv,
    const int* __restrict__ Q, const float* __restrict__ scale,
    const int* __restrict__ hkey, const int* __restrict__ hval,
    int* __restrict__ tabi, float* __restrict__ tabf) {
    const int j = blockIdx.x * 256 + threadIdx.x;
    const int r = oidx[2 * j], c = oidx[2 * j + 1];
    const int key = r * IN_F + c;
    unsigned s = hslot(key);
    while (hkey[s] != key) s = (s + 1) & (HSLOTS - 1);
    if (hval[s] != j) { tabi[j] = -1; tabf[j] = 0.f; return; }   // later dup wins
    const float deq = __bfloat162float(__float2bfloat16(
        (float)Q[(size_t)r * IN_F + c] * scale[r]));
    tabi[j] = (r << 16) | c;
    tabf[j] = outv[j] - deq;
}

// ---- main: fused GEMM, 2-phase dbuf, counted vmcnt, raw barriers ----
__global__ __launch_bounds__(256) void qgemm3(
    const __hip_bfloat16* __restrict__ Xb,
    const int*   __restrict__ Q,
    const float* __restrict__ scale,
    const float* __restrict__ bias,
    const int*   __restrict__ tabi,
    const float* __restrict__ tabf,
    float* __restrict__ out)
{
    __shared__ __hip_bfloat16 sA[2][BM * BK];   // 32 KB, chunk-swizzled
    __shared__ __hip_bfloat16 sB[2][BN * BK];   // 16 KB, chunk-swizzled
    __shared__ int   list[256];
    __shared__ float ldel[256];
    __shared__ int   lcount;

    const int tid  = threadIdx.x;
    const int wave = tid >> 6;
    const int lane = tid & 63;

    // XCD-aware swizzle; 4 consecutive tiles share one Q panel (L2 reuse).
    const int lin = blockIdx.x;
    const int t0  = (lin & 7) * (NWG / 8) + (lin >> 3);
    const int col0 = (t0 >> 2) * BN;
    const int row0 = (t0 & 3) * BM;

    const int wm = (wave >> 1) * 64;
    const int wn = (wave & 1) * 32;
    const int fr = lane & 15;         // fragment row within 16
    const int fc = lane >> 4;         // k-chunk group 0..3

    f32x4 acc[4][2] = {};

    // A staging via global_load_lds: wave issues 4 loads, LDS linear dest;
    // SOURCE chunk XOR-swizzled (m173) so LDS chunk s of row r = logical s^(r&7).
    const int arow = wave * 32 + (lane >> 3);
    const __hip_bfloat16* asrc =
        Xb + (size_t)(row0 + arow) * IN_F + (((lane & 7) ^ (lane >> 3)) * 8);
    auto issueA = [&](int buf, int k0) {
        #pragma unroll
        for (int i = 0; i < 4; ++i)
            __builtin_amdgcn_global_load_lds(
                (const __attribute__((address_space(1))) void*)(asrc + (size_t)i * 8 * IN_F + k0),
                (__attribute__((address_space(3))) void*)&sA[buf][(wave * 4 + i) * 8 * BK],
                16, 0, 0);
    };

    // B staging: thread covers Q row srb, 16 ints at k-offset skb; convert to
    // bf16 and ds_write with the same XOR chunk swizzle.
    const int srb = tid >> 2;
    const int skb = (tid & 3) * 16;
    const int* bsrc = Q + (size_t)(col0 + srb) * IN_F + skb;
    const float bscale = scale[col0 + srb];
    int4v b0, b1, b2, b3;
    auto writeB = [&](int buf) {
        Pack8 v0, v1;
        #pragma unroll
        for (int i = 0; i < 4; ++i) {
            v0.h[i]     = __float2bfloat16((float)b0[i] * bscale);
            v0.h[4 + i] = __float2bfloat16((float)b1[i] * bscale);
            v1.h[i]     = __float2bfloat16((float)b2[i] * bscale);
            v1.h[4 + i] = __float2bfloat16((float)b3[i] * bscale);
        }
        const int c0 = (tid & 3) * 2;
        const int s7 = srb & 7;
        *(bf16x8*)&sB[buf][srb * BK + ((c0 ^ s7) * 8)]       = v0.v;
        *(bf16x8*)&sB[buf][srb * BK + (((c0 + 1) ^ s7) * 8)] = v1.v;
    };

    // Prologue: tile0 into buf0, tile1 B-regs in flight across the barrier.
    issueA(0, 0);
    b0 = *(const int4v*)(bsrc + 0);
    b1 = *(const int4v*)(bsrc + 4);
    b2 = *(const int4v*)(bsrc + 8);
    b3 = *(const int4v*)(bsrc + 12);
    writeB(0);
    b0 = *(const int4v*)(bsrc + BK + 0);
    b1 = *(const int4v*)(bsrc + BK + 4);
    b2 = *(const int4v*)(bsrc + BK + 8);
    b3 = *(const int4v*)(bsrc + BK + 12);
    asm volatile("s_waitcnt vmcnt(4) lgkmcnt(0)" ::: "memory");
    __builtin_amdgcn_s_barrier();

    for (int t = 0; t < NT; ++t) {
        const int cur = t & 1;
        if (t + 1 < NT) issueA(cur ^ 1, (t + 1) * BK);

        // Fragment reads (swizzled slots; bank-balanced).
        bf16x8 fa[2][4], fb[2][2];
        #pragma unroll
        for (int kk = 0; kk < 2; ++kk) {
            #pragma unroll
            for (int mi = 0; mi < 4; ++mi) {
                const int row = wm + mi * 16 + fr;
                fa[kk][mi] = *(const bf16x8*)&sA[cur][row * BK + (((kk * 4 + fc) ^ (row & 7)) * 8)];
            }
            #pragma unroll
            for (int ni = 0; ni < 2; ++ni) {
                const int row = wn + ni * 16 + fr;
                fb[kk][ni] = *(const bf16x8*)&sB[cur][row * BK + (((kk * 4 + fc) ^ (row & 7)) * 8)];
            }
        }
        // Convert+write next B tile, then issue t+2 B-reg loads.
        if (t + 1 < NT) writeB(cur ^ 1);
        if (t + 2 < NT) {
            b0 = *(const int4v*)(bsrc + (t + 2) * BK + 0);
            b1 = *(const int4v*)(bsrc + (t + 2) * BK + 4);
            b2 = *(const int4v*)(bsrc + (t + 2) * BK + 8);
            b3 = *(const int4v*)(bsrc + (t + 2) * BK + 12);
        }
        #pragma unroll
        for (int kk = 0; kk < 2; ++kk)
            #pragma unroll
            for (int mi = 0; mi < 4; ++mi)
                #pragma unroll
                for (int ni = 0; ni < 2; ++ni)
                    acc[mi][ni] = __builtin_amdgcn_mfma_f32_16x16x32_bf16(
                        fa[kk][mi], fb[kk][ni], acc[mi][ni], 0, 0, 0);

        // Publish: A gload_lds + B ds_write done; keep t+2 B-regs in flight.
        if (t + 2 < NT)
            asm volatile("s_waitcnt vmcnt(4) lgkmcnt(0)" ::: "memory");
        else
            asm volatile("s_waitcnt vmcnt(0) lgkmcnt(0)" ::: "memory");
        __builtin_amdgcn_s_barrier();
    }

    // Outlier deltas -> registers (no RMW, no atomics on global).
    if (tid == 0) lcount = 0;
    __syncthreads();
    for (int c = tid; c < NOUT; c += 256) {
        const int p = tabi[c];
        const int r = p >> 16;
        if (r >= col0 && r < col0 + BN) {
            const int pos = atomicAdd(&lcount, 1);
            if (pos < 256) { list[pos] = p; ldel[pos] = tabf[c]; }
        }
    }
    __syncthreads();
    const int nm = lcount < 256 ? lcount : 256;
    for (int u = 0; u < nm; ++u) {
        const int p    = list[u];
        const int ocl  = (p >> 16) - col0;   // 0..63
        const int ocol = p & 0xFFFF;
        if (((ocl >> 5) == (wave & 1)) && ((lane & 15) == (ocl & 15))) {
            const int ni = (ocl >> 4) & 1;
            const float d = ldel[u];
            #pragma unroll
            for (int mi = 0; mi < 4; ++mi)
                #pragma unroll
                for (int r2 = 0; r2 < 4; ++r2) {
                    const int grow = row0 + wm + mi * 16 + fc * 4 + r2;
                    acc[mi][ni][r2] += d * __bfloat162float(Xb[(size_t)grow * IN_F + ocol]);
                }
        }
    }

    // Epilogue: bias + store. C/D: col=lane&15, row=(lane>>4)*4+reg.
    const int er = fc * 4;
    const int ec = fr;
    #pragma unroll
    for (int ni = 0; ni < 2; ++ni) {
        const int gcol = col0 + wn + ni * 16 + ec;
        const float bv = bias[gcol];
        #pragma unroll
        for (int mi = 0; mi < 4; ++mi) {
            const int grow = row0 + wm + mi * 16 + er;
            #pragma unroll
            for (int r = 0; r < 4; ++r)
                out[(size_t)(grow + r) * OUT_F + gcol] = acc[mi][ni][r] + bv;
        }
    }
}

extern "C" void kernel_launch(void* const* d_in, const int* in_sizes, int n_in,
                              void* d_out, int out_size, void* d_ws, size_t ws_size,
                              hipStream_t stream) {
    const float* x    = (const float*)d_in[0];
    const int*   q    = (const int*)d_in[1];
    const float* qs   = (const float*)d_in[2];
    const float* qo   = (const float*)d_in[3];
    const int*   qi   = (const int*)d_in[4];
    const float* bias = (const float*)d_in[5];
    float* out = (float*)d_out;

    __hip_bfloat16* Xb = (__hip_bfloat16*)d_ws;
    int*   tabi = (int*)((char*)d_ws + WS_TAB_I);
    float* tabf = (float*)((char*)d_ws + WS_TAB_F);
    int*   hkey = (int*)((char*)d_ws + WS_HKEY);
    int*   hval = (int*)((char*)d_ws + WS_HVAL);

    prep_x<<<dim3(SEQ * IN_F / 2048), 256, 0, stream>>>(x, Xb);
    prep_hinit<<<dim3(HSLOTS / 256), 256, 0, stream>>>(hkey, hval);
    prep_hins<<<dim3(NOUT / 256), 256, 0, stream>>>(qi, hkey, hval);
    prep_tab<<<dim3(NOUT / 256), 256, 0, stream>>>(qi, qo, q, qs, hkey, hval, tabi, tabf);
    qgemm3<<<dim3(NWG), 256, 0, stream>>>(Xb, q, qs, bias, tabi, tabf, out);
}